// Round 2
// baseline (855.807 us; speedup 1.0000x reference)
//
#include <hip/hip_runtime.h>
#include <math.h>

#define N_ROWS  65536
#define EDIM    256
#define NE      1024
#define BETA    0.25f
#define LAMBDA  0.99f

// ---------------- ws layout (float units) ----------------
// [0]        loss accumulator
// [64]       e_sq[1024]      (numpy-exact fp32 row sums of emb*emb)
// [2048]     e_t[256*1024]   (transposed embedding, e_t[k*NE+j])
// [264192]   zsq[65536]      (numpy-exact fp32 row sums of z*z)
// [329728]   idx[65536] (int)
// [395264]   counts[1024]
// total 396288 floats = 1.55 MB

// out layout (float units): loss, z_q_st, idx, perplexity, N_t, m_t
#define O_ZQ   1
#define O_IDX  16777217
#define O_PERP 16842753
#define O_NT   16842754
#define O_MT   16843778

// ---------------------------------------------------------------------------
// prep: transpose embedding -> e_t, zero loss accumulator
__global__ __launch_bounds__(64) void prep_kernel(const float* __restrict__ emb,
                                                  float* __restrict__ e_t,
                                                  float* __restrict__ loss_acc) {
    int j = blockIdx.x;          // code id
    int l = threadIdx.x;         // 0..63
    float4 v = ((const float4*)(emb + j * EDIM))[l];
    int k = 4 * l;
    e_t[(k + 0) * NE + j] = v.x;
    e_t[(k + 1) * NE + j] = v.y;
    e_t[(k + 2) * NE + j] = v.z;
    e_t[(k + 3) * NE + j] = v.w;
    if (j == 0 && l == 0) *loss_acc = 0.0f;
}

// ---------------------------------------------------------------------------
// sq_kernel: numpy-pairwise-exact fp32 sum of squares per row of 256.
// numpy: n=256 -> pairwise(0:128) + pairwise(128:256); each 128-block uses 8
// stride-8 accumulators (seq adds in i order), combined
// ((r0+r1)+(r2+r3))+((r4+r5)+(r6+r7)). Elementwise square is rounded FIRST
// (numpy materializes zf*zf) -> __fmul_rn/__fadd_rn to forbid fma contraction.
// 16 lanes per row: lane q = h*8+j handles accumulator r[j] of half h.
__global__ __launch_bounds__(256) void sq_kernel(const float* __restrict__ src,
                                                 float* __restrict__ dst) {
    const int tid = threadIdx.x;
    const int grp = tid >> 4;          // 16 rows per block
    const int q   = tid & 15;
    const int row = blockIdx.x * 16 + grp;
    const int h = q >> 3, j = q & 7;
    const float* __restrict__ p = src + (size_t)row * EDIM + h * 128 + j;
    float acc = __fmul_rn(p[0], p[0]);
    #pragma unroll
    for (int t = 1; t < 16; ++t) {
        float v = p[8 * t];
        acc = __fadd_rn(acc, __fmul_rn(v, v));
    }
    // combine: ((r0+r1)+(r2+r3))+((r4+r5)+(r6+r7)) per half, then half1+half2.
    // IEEE add is commutative -> xor-butterfly reproduces the exact tree.
    acc = __fadd_rn(acc, __shfl_xor(acc, 1));
    acc = __fadd_rn(acc, __shfl_xor(acc, 2));
    acc = __fadd_rn(acc, __shfl_xor(acc, 4));
    acc = __fadd_rn(acc, __shfl_xor(acc, 8));
    if (q == 0) dst[row] = acc;
}

// ---------------------------------------------------------------------------
// dist_argmin: block = 32 rows x 1024 cols, 512 threads, TM=32 TN=2.
// dot accumulated as a SEQUENTIAL-k fp32 FMA chain (matches BLAS microkernel
// structure). d = fl32(fl32(zsq+esq) - 2*dot): the +zsq (~256) quantizes d to
// ~1.5e-5, making ties exact fp32 ties; argmin breaks ties to smallest index
// (numpy first-occurrence).
__global__ __launch_bounds__(512) void dist_kernel(const float* __restrict__ z,
                                                   const float* __restrict__ e_t,
                                                   const float* __restrict__ e_sq,
                                                   const float* __restrict__ zsq,
                                                   int* __restrict__ idx_out) {
    const int row0 = blockIdx.x * 32;
    const int col0 = threadIdx.x * 2;
    const float* __restrict__ zb = z + (size_t)row0 * EDIM;

    float acc0[32], acc1[32];
    #pragma unroll
    for (int r = 0; r < 32; ++r) { acc0[r] = 0.0f; acc1[r] = 0.0f; }

    #pragma unroll 2
    for (int k0 = 0; k0 < EDIM; k0 += 4) {
        float2 b0 = *(const float2*)(e_t + (k0 + 0) * NE + col0);
        float2 b1 = *(const float2*)(e_t + (k0 + 1) * NE + col0);
        float2 b2 = *(const float2*)(e_t + (k0 + 2) * NE + col0);
        float2 b3 = *(const float2*)(e_t + (k0 + 3) * NE + col0);
        #pragma unroll
        for (int r = 0; r < 32; ++r) {
            float4 a = *(const float4*)(zb + r * EDIM + k0);  // uniform -> s_load
            acc0[r] += a.x * b0.x; acc1[r] += a.x * b0.y;     // k-sequential fma
            acc0[r] += a.y * b1.x; acc1[r] += a.y * b1.y;
            acc0[r] += a.z * b2.x; acc1[r] += a.z * b2.y;
            acc0[r] += a.w * b3.x; acc1[r] += a.w * b3.y;
        }
    }

    __shared__ float lv[8][32];
    __shared__ int   li[8][32];
    const int w = threadIdx.x >> 6, lane = threadIdx.x & 63;
    const float eq0 = e_sq[col0], eq1 = e_sq[col0 + 1];

    #pragma unroll
    for (int r = 0; r < 32; ++r) {
        float zq = zsq[row0 + r];                               // uniform -> s_load
        float d0 = __fsub_rn(__fadd_rn(zq, eq0), __fmul_rn(2.0f, acc0[r]));
        float d1 = __fsub_rn(__fadd_rn(zq, eq1), __fmul_rn(2.0f, acc1[r]));
        float bv; int bi;
        if (d0 <= d1) { bv = d0; bi = col0; } else { bv = d1; bi = col0 + 1; }
        #pragma unroll
        for (int m = 1; m < 64; m <<= 1) {
            float wv = __shfl_xor(bv, m);
            int   wi = __shfl_xor(bi, m);
            if (wv < bv || (wv == bv && wi < bi)) { bv = wv; bi = wi; }
        }
        if (lane == 0) { lv[w][r] = bv; li[w][r] = bi; }
    }
    __syncthreads();
    if (threadIdx.x < 32) {
        int r = threadIdx.x;
        float bv = lv[0][r]; int bi = li[0][r];
        #pragma unroll
        for (int ww = 1; ww < 8; ++ww) {
            float wv = lv[ww][r]; int wi = li[ww][r];
            if (wv < bv || (wv == bv && wi < bi)) { bv = wv; bi = wi; }
        }
        idx_out[row0 + r] = bi;
    }
}

// ---------------------------------------------------------------------------
// gather: z_q_st = embedding[idx]; loss partial sums; idx as float
__global__ __launch_bounds__(256) void gather_kernel(const float* __restrict__ z,
                                                     const float* __restrict__ emb,
                                                     const int* __restrict__ idx,
                                                     float* __restrict__ out_zq,
                                                     float* __restrict__ out_idx,
                                                     float* __restrict__ loss_acc) {
    int sub = threadIdx.x >> 6, lane = threadIdx.x & 63;
    int row = blockIdx.x * 4 + sub;
    int id = idx[row];
    float4 e = ((const float4*)(emb + (size_t)id * EDIM))[lane];
    float4 zv = ((const float4*)(z + (size_t)row * EDIM))[lane];
    float* o = out_zq + (size_t)row * EDIM + lane * 4;   // out+1 base: scalar stores
    o[0] = e.x; o[1] = e.y; o[2] = e.z; o[3] = e.w;
    float dx = e.x - zv.x, dy = e.y - zv.y, dz = e.z - zv.z, dw = e.w - zv.w;
    float lp = dx * dx + dy * dy + dz * dz + dw * dw;
    #pragma unroll
    for (int m = 32; m; m >>= 1) lp += __shfl_down(lp, m);
    __shared__ float red[4];
    if (lane == 0) { red[sub] = lp; out_idx[row] = (float)id; }
    __syncthreads();
    if (threadIdx.x == 0) atomicAdd(loss_acc, red[0] + red[1] + red[2] + red[3]);
}

// ---------------------------------------------------------------------------
// stats: one block per code; scan idx, gather matching z rows, EMA update
#define CHUNK 8192
__global__ __launch_bounds__(256) void stats_kernel(const float* __restrict__ z,
                                                    const int* __restrict__ idx,
                                                    const float* __restrict__ N_t,
                                                    const float* __restrict__ m_t,
                                                    float* __restrict__ outN,
                                                    float* __restrict__ outM,
                                                    float* __restrict__ counts) {
    const int j = blockIdx.x;
    __shared__ int list[CHUNK];
    __shared__ int cnt_s;
    __shared__ float red[4 * 256];
    const int tid = threadIdx.x, w = tid >> 6, lane = tid & 63;
    float4 acc = make_float4(0.f, 0.f, 0.f, 0.f);
    int total = 0;
    for (int c = 0; c < N_ROWS; c += CHUNK) {
        if (tid == 0) cnt_s = 0;
        __syncthreads();
        for (int i = tid; i < CHUNK; i += 256) {
            if (idx[c + i] == j) { int p = atomicAdd(&cnt_s, 1); list[p] = c + i; }
        }
        __syncthreads();
        int m = cnt_s;
        total += m;
        for (int e = w; e < m; e += 4) {
            float4 v = ((const float4*)(z + (size_t)list[e] * EDIM))[lane];
            acc.x += v.x; acc.y += v.y; acc.z += v.z; acc.w += v.w;
        }
        __syncthreads();
    }
    *(float4*)(red + w * 256 + lane * 4) = acc;
    __syncthreads();
    float s = red[tid] + red[256 + tid] + red[512 + tid] + red[768 + tid];
    float mold = m_t[(size_t)j * EDIM + tid];
    outM[(size_t)j * EDIM + tid] = (total > 0) ? mold * LAMBDA + s * (1.0f - LAMBDA) : mold;
    if (tid == 0) {
        float Nold = N_t[j];
        outN[j] = (total > 0) ? Nold * LAMBDA + (float)total * (1.0f - LAMBDA) : Nold;
        counts[j] = (float)total;
    }
}

// ---------------------------------------------------------------------------
// finalize: loss scale + perplexity from counts
__global__ __launch_bounds__(256) void final_kernel(const float* __restrict__ counts,
                                                    const float* __restrict__ loss_acc,
                                                    float* __restrict__ out_loss,
                                                    float* __restrict__ out_perp) {
    const int tid = threadIdx.x, w = tid >> 6, lane = tid & 63;
    float h = 0.f;
    for (int c = tid; c < NE; c += 256) {
        float em = counts[c] * (1.0f / (float)N_ROWS);
        h += em * logf(em + 1e-10f);
    }
    #pragma unroll
    for (int m = 32; m; m >>= 1) h += __shfl_down(h, m);
    __shared__ float red[4];
    if (lane == 0) red[w] = h;
    __syncthreads();
    if (tid == 0) {
        float H = red[0] + red[1] + red[2] + red[3];
        out_perp[0] = expf(-H);
        out_loss[0] = BETA * loss_acc[0] * (1.0f / (float)(N_ROWS * EDIM));
    }
}

// ---------------------------------------------------------------------------
extern "C" void kernel_launch(void* const* d_in, const int* in_sizes, int n_in,
                              void* d_out, int out_size, void* d_ws, size_t ws_size,
                              hipStream_t stream) {
    const float* z   = (const float*)d_in[0];
    const float* emb = (const float*)d_in[1];
    const float* N_t = (const float*)d_in[2];
    const float* m_t = (const float*)d_in[3];
    float* out = (float*)d_out;
    float* ws  = (float*)d_ws;

    float* loss_acc = ws;
    float* e_sq     = ws + 64;
    float* e_t      = ws + 2048;
    float* zsq      = ws + 264192;
    int*   idx1     = (int*)(ws + 329728);
    float* counts   = ws + 395264;

    prep_kernel<<<NE, 64, 0, stream>>>(emb, e_t, loss_acc);
    sq_kernel<<<NE / 16, 256, 0, stream>>>(emb, e_sq);
    sq_kernel<<<N_ROWS / 16, 256, 0, stream>>>(z, zsq);
    dist_kernel<<<N_ROWS / 32, 512, 0, stream>>>(z, e_t, e_sq, zsq, idx1);
    gather_kernel<<<N_ROWS / 4, 256, 0, stream>>>(z, emb, idx1, out + O_ZQ, out + O_IDX, loss_acc);
    stats_kernel<<<NE, 256, 0, stream>>>(z, idx1, N_t, m_t, out + O_NT, out + O_MT, counts);
    final_kernel<<<1, 256, 0, stream>>>(counts, loss_acc, out + 0, out + O_PERP);
}

// Round 3
// 778.000 us; speedup vs baseline: 1.1000x; 1.1000x over previous
//
#include <hip/hip_runtime.h>
#include <math.h>

#define N_ROWS  65536
#define EDIM    256
#define NE      1024
#define BETA    0.25f
#define LAMBDA  0.99f

// ---------------- ws layout (float units) ----------------
// [0]        loss accumulator
// [64]       e_sq[1024]      (numpy-exact fp32 row sums of emb*emb)
// [2048]     e_t[256*1024]   (transposed embedding, e_t[k*NE+j])
// [264192]   idx[65536] (int)
// [329728]   counts[1024]

// out layout (float units): loss, z_q_st, idx, perplexity, N_t, m_t
#define O_ZQ   1
#define O_IDX  16777217
#define O_PERP 16842753
#define O_NT   16842754
#define O_MT   16843778

// ---------------------------------------------------------------------------
// prep: transpose embedding -> e_t, zero loss accumulator
__global__ __launch_bounds__(64) void prep_kernel(const float* __restrict__ emb,
                                                  float* __restrict__ e_t,
                                                  float* __restrict__ loss_acc) {
    int j = blockIdx.x;          // code id
    int l = threadIdx.x;         // 0..63
    float4 v = ((const float4*)(emb + j * EDIM))[l];
    int k = 4 * l;
    e_t[(k + 0) * NE + j] = v.x;
    e_t[(k + 1) * NE + j] = v.y;
    e_t[(k + 2) * NE + j] = v.z;
    e_t[(k + 3) * NE + j] = v.w;
    if (j == 0 && l == 0) *loss_acc = 0.0f;
}

// ---------------------------------------------------------------------------
// sq_kernel (emb only now): numpy-pairwise-exact fp32 sum of squares, row of
// 256 = two 128-halves, each via 8 stride-8 accumulators combined
// ((r0+r1)+(r2+r3))+((r4+r5)+(r6+r7)); __fmul_rn/__fadd_rn forbid contraction.
__global__ __launch_bounds__(256) void sq_kernel(const float* __restrict__ src,
                                                 float* __restrict__ dst) {
    const int tid = threadIdx.x;
    const int grp = tid >> 4;          // 16 rows per block
    const int q   = tid & 15;
    const int row = blockIdx.x * 16 + grp;
    const int h = q >> 3, j = q & 7;
    const float* __restrict__ p = src + (size_t)row * EDIM + h * 128 + j;
    float acc = __fmul_rn(p[0], p[0]);
    #pragma unroll
    for (int t = 1; t < 16; ++t) {
        float v = p[8 * t];
        acc = __fadd_rn(acc, __fmul_rn(v, v));
    }
    acc = __fadd_rn(acc, __shfl_xor(acc, 1));
    acc = __fadd_rn(acc, __shfl_xor(acc, 2));
    acc = __fadd_rn(acc, __shfl_xor(acc, 4));
    acc = __fadd_rn(acc, __shfl_xor(acc, 8));
    if (q == 0) dst[row] = acc;
}

// ---------------------------------------------------------------------------
// dist (fused): 32 rows x 1024 cols per block, 512 threads, TN=2.
//  - A-tile staged in LDS -> K-loop A reads are wave-uniform ds_read_b128
//    broadcasts (LDS pipe), leaving VALU ~pure FMA.
//  - zsq computed in-kernel from the LDS tile with the numpy-exact tree.
//  - epilogue: argmin (bit-identical semantics to R2), z_q gather+store,
//    loss partials, idx outputs. dot FMA chain order is unchanged vs R2.
__global__ __launch_bounds__(512) void dist_kernel(const float* __restrict__ z,
                                                   const float* __restrict__ e_t,
                                                   const float* __restrict__ e_sq,
                                                   const float* __restrict__ emb,
                                                   int* __restrict__ idx_out,
                                                   float* __restrict__ out_zq,
                                                   float* __restrict__ out_idx,
                                                   float* __restrict__ loss_acc) {
    __shared__ __align__(16) float a_lds[32 * EDIM];   // 32 KB
    __shared__ float lv[8][32];
    __shared__ int   li[8][32];
    __shared__ float zsq_s[32];
    __shared__ int   idx_s[32];
    __shared__ float lred[8];

    const int tid  = threadIdx.x;
    const int row0 = blockIdx.x * 32;

    // ---- stage A: 8192 floats, coalesced float4 ----
    {
        const float4* __restrict__ src = (const float4*)(z + (size_t)row0 * EDIM);
        float4* dst = (float4*)a_lds;
        #pragma unroll
        for (int i = 0; i < 4; ++i) dst[tid + 512 * i] = src[tid + 512 * i];
    }
    __syncthreads();

    // ---- zsq: numpy-pairwise-exact, 16 lanes per row ----
    {
        const int row = tid >> 4, q = tid & 15, h = q >> 3, j = q & 7;
        const float* p = a_lds + row * EDIM + h * 128 + j;
        float acc = __fmul_rn(p[0], p[0]);
        #pragma unroll
        for (int t = 1; t < 16; ++t) {
            float v = p[8 * t];
            acc = __fadd_rn(acc, __fmul_rn(v, v));
        }
        acc = __fadd_rn(acc, __shfl_xor(acc, 1));
        acc = __fadd_rn(acc, __shfl_xor(acc, 2));
        acc = __fadd_rn(acc, __shfl_xor(acc, 4));
        acc = __fadd_rn(acc, __shfl_xor(acc, 8));
        if (q == 0) zsq_s[row] = acc;
    }
    __syncthreads();

    // ---- K-loop: k-sequential fp32 FMA chain (bit-identical order to R2) ----
    const int col0 = tid * 2;
    const float* __restrict__ bp = e_t + col0;
    float acc0[32], acc1[32];
    #pragma unroll
    for (int r = 0; r < 32; ++r) { acc0[r] = 0.0f; acc1[r] = 0.0f; }

    #pragma unroll 2
    for (int k0 = 0; k0 < EDIM; k0 += 4) {
        float2 b0 = *(const float2*)(bp + (k0 + 0) * NE);
        float2 b1 = *(const float2*)(bp + (k0 + 1) * NE);
        float2 b2 = *(const float2*)(bp + (k0 + 2) * NE);
        float2 b3 = *(const float2*)(bp + (k0 + 3) * NE);
        #pragma unroll
        for (int r = 0; r < 32; ++r) {
            float4 a = *(const float4*)(a_lds + r * EDIM + k0);  // uniform -> broadcast ds_read_b128
            acc0[r] += a.x * b0.x; acc1[r] += a.x * b0.y;
            acc0[r] += a.y * b1.x; acc1[r] += a.y * b1.y;
            acc0[r] += a.z * b2.x; acc1[r] += a.z * b2.y;
            acc0[r] += a.w * b3.x; acc1[r] += a.w * b3.y;
        }
    }

    // ---- argmin: per-thread 2 cols -> wave butterfly -> cross-wave merge ----
    const int w = tid >> 6, lane = tid & 63;
    const float eq0 = e_sq[col0], eq1 = e_sq[col0 + 1];

    #pragma unroll
    for (int r = 0; r < 32; ++r) {
        float zq = zsq_s[r];
        float d0 = __fsub_rn(__fadd_rn(zq, eq0), __fmul_rn(2.0f, acc0[r]));
        float d1 = __fsub_rn(__fadd_rn(zq, eq1), __fmul_rn(2.0f, acc1[r]));
        float bv; int bi;
        if (d0 <= d1) { bv = d0; bi = col0; } else { bv = d1; bi = col0 + 1; }
        #pragma unroll
        for (int m = 1; m < 64; m <<= 1) {
            float wv = __shfl_xor(bv, m);
            int   wi = __shfl_xor(bi, m);
            if (wv < bv || (wv == bv && wi < bi)) { bv = wv; bi = wi; }
        }
        if (lane == 0) { lv[w][r] = bv; li[w][r] = bi; }
    }
    __syncthreads();
    if (tid < 32) {
        int r = tid;
        float bv = lv[0][r]; int bi = li[0][r];
        #pragma unroll
        for (int ww = 1; ww < 8; ++ww) {
            float wv = lv[ww][r]; int wi = li[ww][r];
            if (wv < bv || (wv == bv && wi < bi)) { bv = wv; bi = wi; }
        }
        idx_out[row0 + r] = bi;
        idx_s[r] = bi;
        out_idx[row0 + r] = (float)bi;
    }
    __syncthreads();

    // ---- z_q gather + store + loss (z from LDS; saves 64 MB re-read) ----
    {
        const int r = w * 4 + (lane >> 4);       // 8 waves x 4 rows
        const int l16 = lane & 15;
        const int id = idx_s[r];
        float4 e  = ((const float4*)(emb + (size_t)id * EDIM))[l16];
        float4 zv = ((const float4*)(a_lds + r * EDIM))[l16];
        float* o = out_zq + (size_t)(row0 + r) * EDIM + l16 * 4;  // base odd-float: scalar stores
        o[0] = e.x; o[1] = e.y; o[2] = e.z; o[3] = e.w;
        float dx = e.x - zv.x, dy = e.y - zv.y, dz = e.z - zv.z, dw = e.w - zv.w;
        float lp = dx * dx + dy * dy + dz * dz + dw * dw;
        #pragma unroll
        for (int m = 32; m; m >>= 1) lp += __shfl_down(lp, m);
        if (lane == 0) lred[w] = lp;
        __syncthreads();
        if (tid == 0) {
            float s = lred[0] + lred[1] + lred[2] + lred[3]
                    + lred[4] + lred[5] + lred[6] + lred[7];
            atomicAdd(loss_acc, s);
        }
    }
}

// ---------------------------------------------------------------------------
// stats: one block per code, 1024 threads (16 waves) to hide idx-scan latency
#define CHUNK 8192
__global__ __launch_bounds__(1024) void stats_kernel(const float* __restrict__ z,
                                                     const int* __restrict__ idx,
                                                     const float* __restrict__ N_t,
                                                     const float* __restrict__ m_t,
                                                     float* __restrict__ outN,
                                                     float* __restrict__ outM,
                                                     float* __restrict__ counts) {
    const int j = blockIdx.x;
    __shared__ int list[CHUNK];        // 32 KB
    __shared__ int cnt_s;
    __shared__ float red[16 * 256];    // 16 KB
    const int tid = threadIdx.x, w = tid >> 6, lane = tid & 63;
    float4 acc = make_float4(0.f, 0.f, 0.f, 0.f);
    int total = 0;
    for (int c = 0; c < N_ROWS; c += CHUNK) {
        if (tid == 0) cnt_s = 0;
        __syncthreads();
        #pragma unroll
        for (int i = 0; i < CHUNK / 1024; ++i) {
            int p = c + tid + i * 1024;
            if (idx[p] == j) { int s = atomicAdd(&cnt_s, 1); list[s] = p; }
        }
        __syncthreads();
        int m = cnt_s;
        total += m;
        for (int e = w; e < m; e += 16) {
            float4 v = ((const float4*)(z + (size_t)list[e] * EDIM))[lane];
            acc.x += v.x; acc.y += v.y; acc.z += v.z; acc.w += v.w;
        }
        __syncthreads();
    }
    *(float4*)(red + w * 256 + lane * 4) = acc;
    __syncthreads();
    if (tid < 256) {
        float s = 0.f;
        #pragma unroll
        for (int ww = 0; ww < 16; ++ww) s += red[ww * 256 + tid];
        float mold = m_t[(size_t)j * EDIM + tid];
        outM[(size_t)j * EDIM + tid] = (total > 0) ? mold * LAMBDA + s * (1.0f - LAMBDA) : mold;
    }
    if (tid == 0) {
        float Nold = N_t[j];
        outN[j] = (total > 0) ? Nold * LAMBDA + (float)total * (1.0f - LAMBDA) : Nold;
        counts[j] = (float)total;
    }
}

// ---------------------------------------------------------------------------
// finalize: loss scale + perplexity from counts
__global__ __launch_bounds__(256) void final_kernel(const float* __restrict__ counts,
                                                    const float* __restrict__ loss_acc,
                                                    float* __restrict__ out_loss,
                                                    float* __restrict__ out_perp) {
    const int tid = threadIdx.x, w = tid >> 6, lane = tid & 63;
    float h = 0.f;
    for (int c = tid; c < NE; c += 256) {
        float em = counts[c] * (1.0f / (float)N_ROWS);
        h += em * logf(em + 1e-10f);
    }
    #pragma unroll
    for (int m = 32; m; m >>= 1) h += __shfl_down(h, m);
    __shared__ float red[4];
    if (lane == 0) red[w] = h;
    __syncthreads();
    if (tid == 0) {
        float H = red[0] + red[1] + red[2] + red[3];
        out_perp[0] = expf(-H);
        out_loss[0] = BETA * loss_acc[0] * (1.0f / (float)(N_ROWS * EDIM));
    }
}

// ---------------------------------------------------------------------------
extern "C" void kernel_launch(void* const* d_in, const int* in_sizes, int n_in,
                              void* d_out, int out_size, void* d_ws, size_t ws_size,
                              hipStream_t stream) {
    const float* z   = (const float*)d_in[0];
    const float* emb = (const float*)d_in[1];
    const float* N_t = (const float*)d_in[2];
    const float* m_t = (const float*)d_in[3];
    float* out = (float*)d_out;
    float* ws  = (float*)d_ws;

    float* loss_acc = ws;
    float* e_sq     = ws + 64;
    float* e_t      = ws + 2048;
    int*   idx1     = (int*)(ws + 264192);
    float* counts   = ws + 329728;

    prep_kernel<<<NE, 64, 0, stream>>>(emb, e_t, loss_acc);
    sq_kernel<<<NE / 16, 256, 0, stream>>>(emb, e_sq);
    dist_kernel<<<N_ROWS / 32, 512, 0, stream>>>(z, e_t, e_sq, emb, idx1,
                                                 out + O_ZQ, out + O_IDX, loss_acc);
    stats_kernel<<<NE, 1024, 0, stream>>>(z, idx1, N_t, m_t, out + O_NT, out + O_MT, counts);
    final_kernel<<<1, 256, 0, stream>>>(counts, loss_acc, out + 0, out + O_PERP);
}